// Round 9
// baseline (237.196 us; speedup 1.0000x reference)
//
#include <hip/hip_runtime.h>

// GCN 2-layer, CSR-gather formulation, padded-bucket CSR build.
//   out[c] = dinv[c] * ( h_s[c] + sum_{e: col=c} h_s[row_e] ) + b,  h_s=(X@W)*dinv
// R18: GEMM tile 128x64 -> 64x64. R17 counters showed k_gemm_f32in at 42us
// (3-4x roofline): grid 782 -> 3 blk/CU (Occ 20%), VALUBusy 31%, and 1.2M LDS
// bank conflicts from the Xs staging write (stride BM+4=132 == 4 mod 32 ->
// 4-way). Fix: BM 64 (grid 1563, ~6 blk/CU, 24 waves/CU), acc 4x4 (lower
// VGPR), pad +1 (stride 65 == 1 mod 32 -> <=2-way, free). Same fp32 math.
// Build chain = R17's verified 1024/512-thread k_bin/k_bucket_sort.
// Lessons: R11 no 4B global scatter; R14 no LDS-atomic scatter; R15/R16 no
// mega-fusion (one VGPR/LDS envelope can't serve all phases).
// Messages bf16, accum fp32. Requires N < 2^17. Int inputs arrive as int32.

#define BKT_SH 7            // 128 nodes per bucket
#define BKT_CAP 4096        // region per bucket (counts ~2046 +- 45; huge margin)
#define CHUNK 6144          // edges per k_bin block
#define NTB 1024            // k_bin threads
#define NTS 512             // k_bucket_sort threads
#define BM 64               // gemm rows/block
#define BK 32

__device__ __forceinline__ unsigned short f2bf(float f) {
    unsigned u = __builtin_bit_cast(unsigned, f);
    u = (u + 0x7FFF + ((u >> 16) & 1)) >> 16;  // RNE
    return (unsigned short)u;
}
__device__ __forceinline__ float bflo(unsigned u) {  // low bf16 of packed pair
    return __builtin_bit_cast(float, u << 16);
}
__device__ __forceinline__ float bfhi(unsigned u) {  // high bf16 of packed pair
    return __builtin_bit_cast(float, u & 0xFFFF0000u);
}

__global__ __launch_bounds__(256) void k_zero_i(int* __restrict__ p, int n) {
    int i = blockIdx.x * 256 + threadIdx.x;
    if (i < n) p[i] = 0;
}

// (A) block-chunked binning, 1024 threads: LDS hist -> LDS scan (t<256) ->
// one count-reservation atomic per (block,bucket) -> LDS sort by bucket ->
// run-coalesced writes into fixed bucket region [bkt*CAP, (bkt+1)*CAP).
__global__ __launch_bounds__(NTB) void k_bin(const int* __restrict__ row,
                                             const int* __restrict__ col,
                                             int* __restrict__ cursor,
                                             unsigned* __restrict__ bentries,
                                             int E) {
    __shared__ unsigned sorted[CHUNK];        // 24 KB packed entries, bucket order
    __shared__ unsigned short bof[CHUNK];     // 12 KB bucket of sorted[i]
    __shared__ int hist[1024];
    __shared__ int ex0[1024];
    __shared__ int cur[1024];
    __shared__ int gbase[1024];
    __shared__ int tsum[256];
    int b = blockIdx.x, t = threadIdx.x;
    int s0 = b * CHUNK;
    int cnt = E - s0; if (cnt > CHUNK) cnt = CHUNK;

    if (t < 1024) hist[t] = 0;
    __syncthreads();
    // pass 1: histogram
    for (int i = t; i < cnt; i += NTB)
        atomicAdd(&hist[col[s0 + i] >> BKT_SH], 1);
    __syncthreads();
    // scan 1024 bins on threads t<256 (each owns bins [4t, 4t+4));
    // all threads execute the __syncthreads.
    {
        int b0 = 0, b1 = 0, b2 = 0, b3 = 0, tot = 0;
        if (t < 256) {
            b0 = hist[4 * t]; b1 = hist[4 * t + 1];
            b2 = hist[4 * t + 2]; b3 = hist[4 * t + 3];
            tot = b0 + b1 + b2 + b3;
            tsum[t] = tot;
        }
        __syncthreads();
#pragma unroll
        for (int d = 1; d < 256; d <<= 1) {
            int x = 0;
            if (t < 256 && t >= d) x = tsum[t - d];
            __syncthreads();
            if (t < 256 && t >= d) tsum[t] += x;
            __syncthreads();
        }
        if (t < 256) {
            int ex = tsum[t] - tot;  // exclusive across thread groups
            ex0[4 * t] = ex;
            ex0[4 * t + 1] = ex + b0;
            ex0[4 * t + 2] = ex + b0 + b1;
            ex0[4 * t + 3] = ex + b0 + b1 + b2;
            cur[4 * t] = ex;
            cur[4 * t + 1] = ex + b0;
            cur[4 * t + 2] = ex + b0 + b1;
            cur[4 * t + 3] = ex + b0 + b1 + b2;
        }
    }
    __syncthreads();
    // reserve: one atomic per non-empty (block,bucket); region base is fixed
    if (t < 1024)
        if (hist[t] > 0) gbase[t] = t * BKT_CAP + atomicAdd(&cursor[t], hist[t]);
    // pass 2: LDS sort by bucket (order within bucket irrelevant)
    for (int i = t; i < cnt; i += NTB) {
        int c = col[s0 + i], r = row[s0 + i];
        int bkt = c >> BKT_SH;
        int p = atomicAdd(&cur[bkt], 1);
        sorted[p] = ((unsigned)(c & ((1 << BKT_SH) - 1)) << 17) | (unsigned)r;
        bof[p] = (unsigned short)bkt;
    }
    __syncthreads();
    // pass 3: run-coalesced global writes (guard against region overflow)
    for (int i = t; i < cnt; i += NTB) {
        int bkt = bof[i];
        int pos = gbase[bkt] + (i - ex0[bkt]);
        if (pos < (bkt + 1) * BKT_CAP) bentries[pos] = sorted[i];
    }
}

// (B) per-bucket counting sort IN PLACE, 512 threads: bentries[b*CAP..] ->
// row indices sorted by destination node; emits start/cnt/dinv per node.
__global__ __launch_bounds__(NTS) void k_bucket_sort(
    unsigned* __restrict__ bentries, const int* __restrict__ cursor,
    int* __restrict__ start, int* __restrict__ cntarr,
    float* __restrict__ dinv, int N) {
    __shared__ int hist[128];
    __shared__ int incl[128];
    __shared__ int cur[128];
    __shared__ int rows[BKT_CAP];  // 16 KB
    int b = blockIdx.x, t = threadIdx.x;
    int base = b * BKT_CAP;
    int cnt = cursor[b];
    if (cnt > BKT_CAP) cnt = BKT_CAP;  // safety clamp (never expected)

    if (t < 128) hist[t] = 0;
    __syncthreads();
    for (int i = t; i < cnt; i += NTS)
        atomicAdd(&hist[bentries[base + i] >> 17], 1);
    __syncthreads();
    if (t < 128) incl[t] = hist[t];
    __syncthreads();
#pragma unroll
    for (int d = 1; d < 128; d <<= 1) {
        int x = (t < 128 && t >= d) ? incl[t - d] : 0;
        __syncthreads();
        if (t < 128 && t >= d) incl[t] += x;
        __syncthreads();
    }
    if (t < 128) {
        int ex = incl[t] - hist[t];  // exclusive within bucket
        int node = (b << BKT_SH) + t;
        if (node < N) {
            start[node] = base + ex;
            cntarr[node] = hist[t];
            dinv[node] = rsqrtf((float)hist[t] + 1.0f);  // +1 self loop
        }
        cur[t] = ex;
    }
    __syncthreads();
    for (int i = t; i < cnt; i += NTS) {
        unsigned en = bentries[base + i];
        int p = atomicAdd(&cur[en >> 17], 1);
        rows[p] = (int)(en & 0x1FFFF);
    }
    __syncthreads();
    for (int i = t; i < cnt; i += NTS) bentries[base + i] = (unsigned)rows[i];
}

// Tiled GEMM + row scale, fp32 input, bf16 output.
// Block = 256 threads -> BM=64 rows x 64 cols, acc 4x4. K chunked by BK=32.
// Pad +1 (stride 65 == 1 mod 32): staging writes <=2-way bank alias (free).
__global__ __launch_bounds__(256) void k_gemm_f32in(
    const float* __restrict__ X, const float* __restrict__ W,
    const float* __restrict__ dinv, unsigned short* __restrict__ outb,
    int N, int K) {
    __shared__ float Xs[BK][BM + 1];
    __shared__ float Ws[BK][64];
    int t = threadIdx.x;
    int bm = blockIdx.x * BM;
    int tm = t >> 4, tn = t & 15;

    float acc[4][4];
#pragma unroll
    for (int i = 0; i < 4; ++i)
#pragma unroll
        for (int j = 0; j < 4; ++j) acc[i][j] = 0.f;

    for (int kb = 0; kb < K; kb += BK) {
        // stage X: 64 rows x 32 k = 512 float4; 2 per thread
#pragma unroll
        for (int it = 0; it < 2; ++it) {
            int idx = t + 256 * it;           // 0..511
            int r = idx >> 3;                 // 0..63
            int k4 = idx & 7;                 // float4 index within BK
            int grow = bm + r;
            float4 v = make_float4(0.f, 0.f, 0.f, 0.f);
            if (grow < N) v = *(const float4*)(X + (size_t)grow * K + kb + k4 * 4);
            Xs[k4 * 4 + 0][r] = v.x;
            Xs[k4 * 4 + 1][r] = v.y;
            Xs[k4 * 4 + 2][r] = v.z;
            Xs[k4 * 4 + 3][r] = v.w;
        }
        // stage W: 32 k x 64 cols = 512 float4; 2 per thread
#pragma unroll
        for (int it = 0; it < 2; ++it) {
            int idx = t + 256 * it;
            ((float4*)Ws)[idx] = ((const float4*)(W + (size_t)kb * 64))[idx];
        }
        __syncthreads();
#pragma unroll
        for (int k = 0; k < BK; ++k) {
            float4 xa = *(const float4*)&Xs[k][tm * 4];
            float4 w = *(const float4*)&Ws[k][tn * 4];
            float xs[4] = {xa.x, xa.y, xa.z, xa.w};
#pragma unroll
            for (int i = 0; i < 4; ++i) {
                acc[i][0] = fmaf(xs[i], w.x, acc[i][0]);
                acc[i][1] = fmaf(xs[i], w.y, acc[i][1]);
                acc[i][2] = fmaf(xs[i], w.z, acc[i][2]);
                acc[i][3] = fmaf(xs[i], w.w, acc[i][3]);
            }
        }
        __syncthreads();
    }
#pragma unroll
    for (int i = 0; i < 4; ++i) {
        int grow = bm + tm * 4 + i;
        if (grow < N) {
            float s = dinv[grow];
            ushort4 v;
            v.x = f2bf(acc[i][0] * s);
            v.y = f2bf(acc[i][1] * s);
            v.z = f2bf(acc[i][2] * s);
            v.w = f2bf(acc[i][3] * s);
            *(ushort4*)(outb + (size_t)grow * 64 + tn * 4) = v;
        }
    }
}

// Tiled GEMM + row scale, bf16 input, bf16 output. Same 64x64 tile shape.
__global__ __launch_bounds__(256) void k_gemm_bf16in(
    const unsigned short* __restrict__ Xb, const float* __restrict__ W,
    const float* __restrict__ dinv, unsigned short* __restrict__ outb,
    int N, int K) {
    __shared__ float Xs[BK][BM + 1];
    __shared__ float Ws[BK][64];
    int t = threadIdx.x;
    int bm = blockIdx.x * BM;
    int tm = t >> 4, tn = t & 15;

    float acc[4][4];
#pragma unroll
    for (int i = 0; i < 4; ++i)
#pragma unroll
        for (int j = 0; j < 4; ++j) acc[i][j] = 0.f;

    for (int kb = 0; kb < K; kb += BK) {
        // stage X: 64 rows x 32 k bf16 = 256 uint4 (8 bf16 each); 1 per thread
        {
            int r = t >> 2;                   // 0..63
            int q = t & 3;                    // 16B chunk: k = q*8..q*8+8
            int grow = bm + r;
            uint4 v = make_uint4(0u, 0u, 0u, 0u);
            if (grow < N) v = *(const uint4*)(Xb + (size_t)grow * K + kb + q * 8);
            int k0 = q * 8;
            Xs[k0 + 0][r] = bflo(v.x); Xs[k0 + 1][r] = bfhi(v.x);
            Xs[k0 + 2][r] = bflo(v.y); Xs[k0 + 3][r] = bfhi(v.y);
            Xs[k0 + 4][r] = bflo(v.z); Xs[k0 + 5][r] = bfhi(v.z);
            Xs[k0 + 6][r] = bflo(v.w); Xs[k0 + 7][r] = bfhi(v.w);
        }
#pragma unroll
        for (int it = 0; it < 2; ++it) {
            int idx = t + 256 * it;           // 0..511 float4s
            ((float4*)Ws)[idx] = ((const float4*)(W + (size_t)kb * 64))[idx];
        }
        __syncthreads();
#pragma unroll
        for (int k = 0; k < BK; ++k) {
            float4 xa = *(const float4*)&Xs[k][tm * 4];
            float4 w = *(const float4*)&Ws[k][tn * 4];
            float xs[4] = {xa.x, xa.y, xa.z, xa.w};
#pragma unroll
            for (int i = 0; i < 4; ++i) {
                acc[i][0] = fmaf(xs[i], w.x, acc[i][0]);
                acc[i][1] = fmaf(xs[i], w.y, acc[i][1]);
                acc[i][2] = fmaf(xs[i], w.z, acc[i][2]);
                acc[i][3] = fmaf(xs[i], w.w, acc[i][3]);
            }
        }
        __syncthreads();
    }
#pragma unroll
    for (int i = 0; i < 4; ++i) {
        int grow = bm + tm * 4 + i;
        if (grow < N) {
            float s = dinv[grow];
            ushort4 v;
            v.x = f2bf(acc[i][0] * s);
            v.y = f2bf(acc[i][1] * s);
            v.z = f2bf(acc[i][2] * s);
            v.w = f2bf(acc[i][3] * s);
            *(ushort4*)(outb + (size_t)grow * 64 + tn * 4) = v;
        }
    }
}

// Gather-aggregate + fused postproc. 8 lanes/node; lane l owns channels
// [8l, 8l+8) as one uint4 (4 packed bf16 pairs). fp32 accumulate.
// acc init = src[node] (self loop). MLP-unrolled x8 (+x4 tail).
// mode 1: relu + bf16 out (dstq). mode 0: fp32 out (dstf).
__global__ __launch_bounds__(256) void k_gather(
    const uint4* __restrict__ srcq, const int* __restrict__ eros,
    const int* __restrict__ start, const int* __restrict__ cntarr,
    const float* __restrict__ dinv, const float* __restrict__ bias,
    float* __restrict__ dstf, uint4* __restrict__ dstq, int N, int mode) {
    int idx = blockIdx.x * 256 + threadIdx.x;
    int node = idx >> 3;
    if (node >= N) return;
    int l = idx & 7;

    uint4 sv = srcq[(size_t)node * 8 + l];  // self loop
    float a0 = bflo(sv.x), a1 = bfhi(sv.x);
    float a2 = bflo(sv.y), a3 = bfhi(sv.y);
    float a4 = bflo(sv.z), a5 = bfhi(sv.z);
    float a6 = bflo(sv.w), a7 = bfhi(sv.w);

    int e = start[node];
    int eend = e + cntarr[node];
    for (; e + 8 <= eend; e += 8) {
        uint4 v[8];
#pragma unroll
        for (int j = 0; j < 8; ++j) {
            int r = eros[e + j];
            v[j] = srcq[(size_t)r * 8 + l];
        }
#pragma unroll
        for (int j = 0; j < 8; ++j) {
            a0 += bflo(v[j].x); a1 += bfhi(v[j].x);
            a2 += bflo(v[j].y); a3 += bfhi(v[j].y);
            a4 += bflo(v[j].z); a5 += bfhi(v[j].z);
            a6 += bflo(v[j].w); a7 += bfhi(v[j].w);
        }
    }
    for (; e + 4 <= eend; e += 4) {
        uint4 v[4];
#pragma unroll
        for (int j = 0; j < 4; ++j) {
            int r = eros[e + j];
            v[j] = srcq[(size_t)r * 8 + l];
        }
#pragma unroll
        for (int j = 0; j < 4; ++j) {
            a0 += bflo(v[j].x); a1 += bfhi(v[j].x);
            a2 += bflo(v[j].y); a3 += bfhi(v[j].y);
            a4 += bflo(v[j].z); a5 += bfhi(v[j].z);
            a6 += bflo(v[j].w); a7 += bfhi(v[j].w);
        }
    }
    for (; e < eend; ++e) {
        int r = eros[e];
        uint4 v = srcq[(size_t)r * 8 + l];
        a0 += bflo(v.x); a1 += bfhi(v.x);
        a2 += bflo(v.y); a3 += bfhi(v.y);
        a4 += bflo(v.z); a5 += bfhi(v.z);
        a6 += bflo(v.w); a7 += bfhi(v.w);
    }
    float sc = dinv[node];
    const float4* bp = (const float4*)bias;
    float4 b0 = bp[l * 2], b1 = bp[l * 2 + 1];
    a0 = a0 * sc + b0.x; a1 = a1 * sc + b0.y;
    a2 = a2 * sc + b0.z; a3 = a3 * sc + b0.w;
    a4 = a4 * sc + b1.x; a5 = a5 * sc + b1.y;
    a6 = a6 * sc + b1.z; a7 = a7 * sc + b1.w;
    if (mode) {  // relu + bf16 pack
        a0 = fmaxf(a0, 0.f); a1 = fmaxf(a1, 0.f);
        a2 = fmaxf(a2, 0.f); a3 = fmaxf(a3, 0.f);
        a4 = fmaxf(a4, 0.f); a5 = fmaxf(a5, 0.f);
        a6 = fmaxf(a6, 0.f); a7 = fmaxf(a7, 0.f);
        uint4 o;
        o.x = (unsigned)f2bf(a0) | ((unsigned)f2bf(a1) << 16);
        o.y = (unsigned)f2bf(a2) | ((unsigned)f2bf(a3) << 16);
        o.z = (unsigned)f2bf(a4) | ((unsigned)f2bf(a5) << 16);
        o.w = (unsigned)f2bf(a6) | ((unsigned)f2bf(a7) << 16);
        dstq[(size_t)node * 8 + l] = o;
    } else {
        float4 o0 = make_float4(a0, a1, a2, a3);
        float4 o1 = make_float4(a4, a5, a6, a7);
        float4* d = (float4*)(dstf + (size_t)node * 64 + l * 8);
        d[0] = o0;
        d[1] = o1;
    }
}

extern "C" void kernel_launch(void* const* d_in, const int* in_sizes, int n_in,
                              void* d_out, int out_size, void* d_ws, size_t ws_size,
                              hipStream_t stream) {
    const float* x = (const float*)d_in[0];
    const int* ei = (const int*)d_in[1];  // int32 per harness contract, [2, E]
    const float* W1 = (const float*)d_in[2];
    const float* b1 = (const float*)d_in[3];
    const float* W2 = (const float*)d_in[4];
    const float* b2 = (const float*)d_in[5];

    int N = in_sizes[0] / 128;  // 100000
    int E = in_sizes[1] / 2;    // 1600000
    const int* row = ei;
    const int* col = ei + E;
    int nb = (N + (1 << BKT_SH) - 1) >> BKT_SH;  // 782 buckets

    char* ws = (char*)d_ws;
    int* cursor = (int*)ws;                          // nb ints @ 0
    int* start = (int*)(ws + (1 << 16));             // N ints @ 64 KB
    int* cntarr = (int*)(ws + (1 << 19));            // N ints @ 512 KB
    float* dinv = (float*)(ws + 960 * 1024);         // N floats @ 960 KB
    unsigned* bentries = (unsigned*)(ws + (2 << 20));    // nb*CAP u32 @ 2 MB (12.8 MB)
    unsigned short* Ab = (unsigned short*)(ws + (15 << 20));  // N*64 bf16 @ 15 MB (12.8 MB)
    unsigned short* Hb = (unsigned short*)d_out;     // bf16 h2 scratch in d_out
    float* OUTF = (float*)d_out;                     // final fp32 output

    int gemmblk = (N + BM - 1) / BM;       // 1563
    int binblk = (E + CHUNK - 1) / CHUNK;  // 261
    int gblk = (N * 8 + 255) / 256;        // 3125

    // --- CSR build (padded buckets; once, shared by both layers) ---
    k_zero_i<<<(nb + 255) / 256, 256, 0, stream>>>(cursor, nb);
    k_bin<<<binblk, NTB, 0, stream>>>(row, col, cursor, bentries, E);
    k_bucket_sort<<<nb, NTS, 0, stream>>>(bentries, cursor, start, cntarr, dinv, N);

    // Layer 1: Ab = bf16((X@W1)*dinv); Hb = bf16(relu(gather(Ab)*dinv + b1))
    k_gemm_f32in<<<gemmblk, 256, 0, stream>>>(x, W1, dinv, Ab, N, 128);
    k_gather<<<gblk, 256, 0, stream>>>((const uint4*)Ab, (const int*)bentries,
                                       start, cntarr, dinv, b1,
                                       nullptr, (uint4*)Hb, N, 1);

    // Layer 2: Ab = bf16((Hb@W2)*dinv); d_out = gather(Ab)*dinv + b2 (fp32)
    k_gemm_bf16in<<<gemmblk, 256, 0, stream>>>(Hb, W2, dinv, Ab, N, 64);
    k_gather<<<gblk, 256, 0, stream>>>((const uint4*)Ab, (const int*)bentries,
                                       start, cntarr, dinv, b2,
                                       OUTF, nullptr, N, 0);
}

// Round 10
// 230.604 us; speedup vs baseline: 1.0286x; 1.0286x over previous
//
#include <hip/hip_runtime.h>

// GCN 2-layer, CSR-gather formulation, padded-bucket CSR build.
//   out[c] = dinv[c] * ( h_s[c] + sum_{e: col=c} h_s[row_e] ) + b,  h_s=(X@W)*dinv
// R19: software-pipelined GEMM staging. R18 ruled out conflicts (0) and tile
// shape (128x64 and 64x64 both 42us); signature VALUBusy 30% + HBM 930 GB/s
// = staging latency exposed (load->barrier->compute serial, 4 K-steps).
// Fix: issue next K-tile's global loads into REGISTERS before the FMA loop,
// ds_write them after the post-compute barrier (T14 issue-early/write-late).
// Single LDS buffer (16.9KB, occupancy kept), +16 VGPR. Same math/epilogue.
// Build chain = R17's verified 1024/512-thread k_bin/k_bucket_sort.
// Lessons: R11 no 4B global scatter; R14 no LDS-atomic scatter; R15/R16 no
// mega-fusion (one VGPR/LDS envelope can't serve all phases).
// Messages bf16, accum fp32. Requires N < 2^17. Int inputs arrive as int32.

#define BKT_SH 7            // 128 nodes per bucket
#define BKT_CAP 4096        // region per bucket (counts ~2046 +- 45; huge margin)
#define CHUNK 6144          // edges per k_bin block
#define NTB 1024            // k_bin threads
#define NTS 512             // k_bucket_sort threads
#define BM 64               // gemm rows/block
#define BK 32

__device__ __forceinline__ unsigned short f2bf(float f) {
    unsigned u = __builtin_bit_cast(unsigned, f);
    u = (u + 0x7FFF + ((u >> 16) & 1)) >> 16;  // RNE
    return (unsigned short)u;
}
__device__ __forceinline__ float bflo(unsigned u) {  // low bf16 of packed pair
    return __builtin_bit_cast(float, u << 16);
}
__device__ __forceinline__ float bfhi(unsigned u) {  // high bf16 of packed pair
    return __builtin_bit_cast(float, u & 0xFFFF0000u);
}

__global__ __launch_bounds__(256) void k_zero_i(int* __restrict__ p, int n) {
    int i = blockIdx.x * 256 + threadIdx.x;
    if (i < n) p[i] = 0;
}

// (A) block-chunked binning, 1024 threads: LDS hist -> LDS scan (t<256) ->
// one count-reservation atomic per (block,bucket) -> LDS sort by bucket ->
// run-coalesced writes into fixed bucket region [bkt*CAP, (bkt+1)*CAP).
__global__ __launch_bounds__(NTB) void k_bin(const int* __restrict__ row,
                                             const int* __restrict__ col,
                                             int* __restrict__ cursor,
                                             unsigned* __restrict__ bentries,
                                             int E) {
    __shared__ unsigned sorted[CHUNK];        // 24 KB packed entries, bucket order
    __shared__ unsigned short bof[CHUNK];     // 12 KB bucket of sorted[i]
    __shared__ int hist[1024];
    __shared__ int ex0[1024];
    __shared__ int cur[1024];
    __shared__ int gbase[1024];
    __shared__ int tsum[256];
    int b = blockIdx.x, t = threadIdx.x;
    int s0 = b * CHUNK;
    int cnt = E - s0; if (cnt > CHUNK) cnt = CHUNK;

    if (t < 1024) hist[t] = 0;
    __syncthreads();
    // pass 1: histogram
    for (int i = t; i < cnt; i += NTB)
        atomicAdd(&hist[col[s0 + i] >> BKT_SH], 1);
    __syncthreads();
    // scan 1024 bins on threads t<256 (each owns bins [4t, 4t+4));
    // all threads execute the __syncthreads.
    {
        int b0 = 0, b1 = 0, b2 = 0, b3 = 0, tot = 0;
        if (t < 256) {
            b0 = hist[4 * t]; b1 = hist[4 * t + 1];
            b2 = hist[4 * t + 2]; b3 = hist[4 * t + 3];
            tot = b0 + b1 + b2 + b3;
            tsum[t] = tot;
        }
        __syncthreads();
#pragma unroll
        for (int d = 1; d < 256; d <<= 1) {
            int x = 0;
            if (t < 256 && t >= d) x = tsum[t - d];
            __syncthreads();
            if (t < 256 && t >= d) tsum[t] += x;
            __syncthreads();
        }
        if (t < 256) {
            int ex = tsum[t] - tot;  // exclusive across thread groups
            ex0[4 * t] = ex;
            ex0[4 * t + 1] = ex + b0;
            ex0[4 * t + 2] = ex + b0 + b1;
            ex0[4 * t + 3] = ex + b0 + b1 + b2;
            cur[4 * t] = ex;
            cur[4 * t + 1] = ex + b0;
            cur[4 * t + 2] = ex + b0 + b1;
            cur[4 * t + 3] = ex + b0 + b1 + b2;
        }
    }
    __syncthreads();
    // reserve: one atomic per non-empty (block,bucket); region base is fixed
    if (t < 1024)
        if (hist[t] > 0) gbase[t] = t * BKT_CAP + atomicAdd(&cursor[t], hist[t]);
    // pass 2: LDS sort by bucket (order within bucket irrelevant)
    for (int i = t; i < cnt; i += NTB) {
        int c = col[s0 + i], r = row[s0 + i];
        int bkt = c >> BKT_SH;
        int p = atomicAdd(&cur[bkt], 1);
        sorted[p] = ((unsigned)(c & ((1 << BKT_SH) - 1)) << 17) | (unsigned)r;
        bof[p] = (unsigned short)bkt;
    }
    __syncthreads();
    // pass 3: run-coalesced global writes (guard against region overflow)
    for (int i = t; i < cnt; i += NTB) {
        int bkt = bof[i];
        int pos = gbase[bkt] + (i - ex0[bkt]);
        if (pos < (bkt + 1) * BKT_CAP) bentries[pos] = sorted[i];
    }
}

// (B) per-bucket counting sort IN PLACE, 512 threads: bentries[b*CAP..] ->
// row indices sorted by destination node; emits start/cnt/dinv per node.
__global__ __launch_bounds__(NTS) void k_bucket_sort(
    unsigned* __restrict__ bentries, const int* __restrict__ cursor,
    int* __restrict__ start, int* __restrict__ cntarr,
    float* __restrict__ dinv, int N) {
    __shared__ int hist[128];
    __shared__ int incl[128];
    __shared__ int cur[128];
    __shared__ int rows[BKT_CAP];  // 16 KB
    int b = blockIdx.x, t = threadIdx.x;
    int base = b * BKT_CAP;
    int cnt = cursor[b];
    if (cnt > BKT_CAP) cnt = BKT_CAP;  // safety clamp (never expected)

    if (t < 128) hist[t] = 0;
    __syncthreads();
    for (int i = t; i < cnt; i += NTS)
        atomicAdd(&hist[bentries[base + i] >> 17], 1);
    __syncthreads();
    if (t < 128) incl[t] = hist[t];
    __syncthreads();
#pragma unroll
    for (int d = 1; d < 128; d <<= 1) {
        int x = (t < 128 && t >= d) ? incl[t - d] : 0;
        __syncthreads();
        if (t < 128 && t >= d) incl[t] += x;
        __syncthreads();
    }
    if (t < 128) {
        int ex = incl[t] - hist[t];  // exclusive within bucket
        int node = (b << BKT_SH) + t;
        if (node < N) {
            start[node] = base + ex;
            cntarr[node] = hist[t];
            dinv[node] = rsqrtf((float)hist[t] + 1.0f);  // +1 self loop
        }
        cur[t] = ex;
    }
    __syncthreads();
    for (int i = t; i < cnt; i += NTS) {
        unsigned en = bentries[base + i];
        int p = atomicAdd(&cur[en >> 17], 1);
        rows[p] = (int)(en & 0x1FFFF);
    }
    __syncthreads();
    for (int i = t; i < cnt; i += NTS) bentries[base + i] = (unsigned)rows[i];
}

// Tiled GEMM + row scale, fp32 input, bf16 output. 64x64 tile, acc 4x4.
// Software-pipelined: next K-tile's global loads issued into registers BEFORE
// the FMA loop; ds_write after the post-compute barrier. Pad +1 (free alias).
__global__ __launch_bounds__(256) void k_gemm_f32in(
    const float* __restrict__ X, const float* __restrict__ W,
    const float* __restrict__ dinv, unsigned short* __restrict__ outb,
    int N, int K) {
    __shared__ float Xs[BK][BM + 1];
    __shared__ float Ws[BK][64];
    int t = threadIdx.x;
    int bm = blockIdx.x * BM;
    int tm = t >> 4, tn = t & 15;
    int sr = t >> 3;                 // staging row base (0..31), +32 for it=1
    int sk4 = t & 7;                 // staging float4 index within BK

    float4 rx0, rx1, rw0, rw1;

#define LOADT(kb)                                                              \
    {                                                                          \
        int g0 = bm + sr, g1 = bm + sr + 32;                                   \
        rx0 = make_float4(0.f, 0.f, 0.f, 0.f);                                 \
        rx1 = make_float4(0.f, 0.f, 0.f, 0.f);                                 \
        if (g0 < N) rx0 = *(const float4*)(X + (size_t)g0 * K + (kb) + sk4 * 4);\
        if (g1 < N) rx1 = *(const float4*)(X + (size_t)g1 * K + (kb) + sk4 * 4);\
        rw0 = ((const float4*)(W + (size_t)(kb) * 64))[t];                     \
        rw1 = ((const float4*)(W + (size_t)(kb) * 64))[t + 256];               \
    }
#define WRITET()                                                               \
    {                                                                          \
        Xs[sk4 * 4 + 0][sr] = rx0.x; Xs[sk4 * 4 + 1][sr] = rx0.y;              \
        Xs[sk4 * 4 + 2][sr] = rx0.z; Xs[sk4 * 4 + 3][sr] = rx0.w;              \
        Xs[sk4 * 4 + 0][sr + 32] = rx1.x; Xs[sk4 * 4 + 1][sr + 32] = rx1.y;    \
        Xs[sk4 * 4 + 2][sr + 32] = rx1.z; Xs[sk4 * 4 + 3][sr + 32] = rx1.w;    \
        ((float4*)Ws)[t] = rw0;                                                \
        ((float4*)Ws)[t + 256] = rw1;                                          \
    }

    float acc[4][4];
#pragma unroll
    for (int i = 0; i < 4; ++i)
#pragma unroll
        for (int j = 0; j < 4; ++j) acc[i][j] = 0.f;

    LOADT(0);
    WRITET();
    __syncthreads();
    for (int kb = 0; kb < K; kb += BK) {
        bool more = (kb + BK) < K;
        if (more) LOADT(kb + BK);    // in flight during compute
#pragma unroll
        for (int k = 0; k < BK; ++k) {
            float4 xa = *(const float4*)&Xs[k][tm * 4];
            float4 w = *(const float4*)&Ws[k][tn * 4];
            float xs[4] = {xa.x, xa.y, xa.z, xa.w};
#pragma unroll
            for (int i = 0; i < 4; ++i) {
                acc[i][0] = fmaf(xs[i], w.x, acc[i][0]);
                acc[i][1] = fmaf(xs[i], w.y, acc[i][1]);
                acc[i][2] = fmaf(xs[i], w.z, acc[i][2]);
                acc[i][3] = fmaf(xs[i], w.w, acc[i][3]);
            }
        }
        __syncthreads();
        if (more) {
            WRITET();
            __syncthreads();
        }
    }
#pragma unroll
    for (int i = 0; i < 4; ++i) {
        int grow = bm + tm * 4 + i;
        if (grow < N) {
            float s = dinv[grow];
            ushort4 v;
            v.x = f2bf(acc[i][0] * s);
            v.y = f2bf(acc[i][1] * s);
            v.z = f2bf(acc[i][2] * s);
            v.w = f2bf(acc[i][3] * s);
            *(ushort4*)(outb + (size_t)grow * 64 + tn * 4) = v;
        }
    }
#undef LOADT
#undef WRITET
}

// Tiled GEMM + row scale, bf16 input, bf16 output. Same 64x64 pipelined shape.
__global__ __launch_bounds__(256) void k_gemm_bf16in(
    const unsigned short* __restrict__ Xb, const float* __restrict__ W,
    const float* __restrict__ dinv, unsigned short* __restrict__ outb,
    int N, int K) {
    __shared__ float Xs[BK][BM + 1];
    __shared__ float Ws[BK][64];
    int t = threadIdx.x;
    int bm = blockIdx.x * BM;
    int tm = t >> 4, tn = t & 15;
    int sr = t >> 2;                 // staging row (0..63)
    int sq = t & 3;                  // 16B chunk: k = sq*8..sq*8+8

    uint4 vx;
    float4 rw0, rw1;

#define LOADT(kb)                                                              \
    {                                                                          \
        int grow = bm + sr;                                                    \
        vx = make_uint4(0u, 0u, 0u, 0u);                                       \
        if (grow < N) vx = *(const uint4*)(Xb + (size_t)grow * K + (kb) + sq * 8);\
        rw0 = ((const float4*)(W + (size_t)(kb) * 64))[t];                     \
        rw1 = ((const float4*)(W + (size_t)(kb) * 64))[t + 256];               \
    }
#define WRITET()                                                               \
    {                                                                          \
        int k0 = sq * 8;                                                       \
        Xs[k0 + 0][sr] = bflo(vx.x); Xs[k0 + 1][sr] = bfhi(vx.x);              \
        Xs[k0 + 2][sr] = bflo(vx.y); Xs[k0 + 3][sr] = bfhi(vx.y);              \
        Xs[k0 + 4][sr] = bflo(vx.z); Xs[k0 + 5][sr] = bfhi(vx.z);              \
        Xs[k0 + 6][sr] = bflo(vx.w); Xs[k0 + 7][sr] = bfhi(vx.w);              \
        ((float4*)Ws)[t] = rw0;                                                \
        ((float4*)Ws)[t + 256] = rw1;                                          \
    }

    float acc[4][4];
#pragma unroll
    for (int i = 0; i < 4; ++i)
#pragma unroll
        for (int j = 0; j < 4; ++j) acc[i][j] = 0.f;

    LOADT(0);
    WRITET();
    __syncthreads();
    for (int kb = 0; kb < K; kb += BK) {
        bool more = (kb + BK) < K;
        if (more) LOADT(kb + BK);    // in flight during compute
#pragma unroll
        for (int k = 0; k < BK; ++k) {
            float4 xa = *(const float4*)&Xs[k][tm * 4];
            float4 w = *(const float4*)&Ws[k][tn * 4];
            float xs[4] = {xa.x, xa.y, xa.z, xa.w};
#pragma unroll
            for (int i = 0; i < 4; ++i) {
                acc[i][0] = fmaf(xs[i], w.x, acc[i][0]);
                acc[i][1] = fmaf(xs[i], w.y, acc[i][1]);
                acc[i][2] = fmaf(xs[i], w.z, acc[i][2]);
                acc[i][3] = fmaf(xs[i], w.w, acc[i][3]);
            }
        }
        __syncthreads();
        if (more) {
            WRITET();
            __syncthreads();
        }
    }
#pragma unroll
    for (int i = 0; i < 4; ++i) {
        int grow = bm + tm * 4 + i;
        if (grow < N) {
            float s = dinv[grow];
            ushort4 v;
            v.x = f2bf(acc[i][0] * s);
            v.y = f2bf(acc[i][1] * s);
            v.z = f2bf(acc[i][2] * s);
            v.w = f2bf(acc[i][3] * s);
            *(ushort4*)(outb + (size_t)grow * 64 + tn * 4) = v;
        }
    }
#undef LOADT
#undef WRITET
}

// Gather-aggregate + fused postproc. 8 lanes/node; lane l owns channels
// [8l, 8l+8) as one uint4 (4 packed bf16 pairs). fp32 accumulate.
// acc init = src[node] (self loop). MLP-unrolled x8 (+x4 tail).
// mode 1: relu + bf16 out (dstq). mode 0: fp32 out (dstf).
__global__ __launch_bounds__(256) void k_gather(
    const uint4* __restrict__ srcq, const int* __restrict__ eros,
    const int* __restrict__ start, const int* __restrict__ cntarr,
    const float* __restrict__ dinv, const float* __restrict__ bias,
    float* __restrict__ dstf, uint4* __restrict__ dstq, int N, int mode) {
    int idx = blockIdx.x * 256 + threadIdx.x;
    int node = idx >> 3;
    if (node >= N) return;
    int l = idx & 7;

    uint4 sv = srcq[(size_t)node * 8 + l];  // self loop
    float a0 = bflo(sv.x), a1 = bfhi(sv.x);
    float a2 = bflo(sv.y), a3 = bfhi(sv.y);
    float a4 = bflo(sv.z), a5 = bfhi(sv.z);
    float a6 = bflo(sv.w), a7 = bfhi(sv.w);

    int e = start[node];
    int eend = e + cntarr[node];
    for (; e + 8 <= eend; e += 8) {
        uint4 v[8];
#pragma unroll
        for (int j = 0; j < 8; ++j) {
            int r = eros[e + j];
            v[j] = srcq[(size_t)r * 8 + l];
        }
#pragma unroll
        for (int j = 0; j < 8; ++j) {
            a0 += bflo(v[j].x); a1 += bfhi(v[j].x);
            a2 += bflo(v[j].y); a3 += bfhi(v[j].y);
            a4 += bflo(v[j].z); a5 += bfhi(v[j].z);
            a6 += bflo(v[j].w); a7 += bfhi(v[j].w);
        }
    }
    for (; e + 4 <= eend; e += 4) {
        uint4 v[4];
#pragma unroll
        for (int j = 0; j < 4; ++j) {
            int r = eros[e + j];
            v[j] = srcq[(size_t)r * 8 + l];
        }
#pragma unroll
        for (int j = 0; j < 4; ++j) {
            a0 += bflo(v[j].x); a1 += bfhi(v[j].x);
            a2 += bflo(v[j].y); a3 += bfhi(v[j].y);
            a4 += bflo(v[j].z); a5 += bfhi(v[j].z);
            a6 += bflo(v[j].w); a7 += bfhi(v[j].w);
        }
    }
    for (; e < eend; ++e) {
        int r = eros[e];
        uint4 v = srcq[(size_t)r * 8 + l];
        a0 += bflo(v.x); a1 += bfhi(v.x);
        a2 += bflo(v.y); a3 += bfhi(v.y);
        a4 += bflo(v.z); a5 += bfhi(v.z);
        a6 += bflo(v.w); a7 += bfhi(v.w);
    }
    float sc = dinv[node];
    const float4* bp = (const float4*)bias;
    float4 b0 = bp[l * 2], b1 = bp[l * 2 + 1];
    a0 = a0 * sc + b0.x; a1 = a1 * sc + b0.y;
    a2 = a2 * sc + b0.z; a3 = a3 * sc + b0.w;
    a4 = a4 * sc + b1.x; a5 = a5 * sc + b1.y;
    a6 = a6 * sc + b1.z; a7 = a7 * sc + b1.w;
    if (mode) {  // relu + bf16 pack
        a0 = fmaxf(a0, 0.f); a1 = fmaxf(a1, 0.f);
        a2 = fmaxf(a2, 0.f); a3 = fmaxf(a3, 0.f);
        a4 = fmaxf(a4, 0.f); a5 = fmaxf(a5, 0.f);
        a6 = fmaxf(a6, 0.f); a7 = fmaxf(a7, 0.f);
        uint4 o;
        o.x = (unsigned)f2bf(a0) | ((unsigned)f2bf(a1) << 16);
        o.y = (unsigned)f2bf(a2) | ((unsigned)f2bf(a3) << 16);
        o.z = (unsigned)f2bf(a4) | ((unsigned)f2bf(a5) << 16);
        o.w = (unsigned)f2bf(a6) | ((unsigned)f2bf(a7) << 16);
        dstq[(size_t)node * 8 + l] = o;
    } else {
        float4 o0 = make_float4(a0, a1, a2, a3);
        float4 o1 = make_float4(a4, a5, a6, a7);
        float4* d = (float4*)(dstf + (size_t)node * 64 + l * 8);
        d[0] = o0;
        d[1] = o1;
    }
}

extern "C" void kernel_launch(void* const* d_in, const int* in_sizes, int n_in,
                              void* d_out, int out_size, void* d_ws, size_t ws_size,
                              hipStream_t stream) {
    const float* x = (const float*)d_in[0];
    const int* ei = (const int*)d_in[1];  // int32 per harness contract, [2, E]
    const float* W1 = (const float*)d_in[2];
    const float* b1 = (const float*)d_in[3];
    const float* W2 = (const float*)d_in[4];
    const float* b2 = (const float*)d_in[5];

    int N = in_sizes[0] / 128;  // 100000
    int E = in_sizes[1] / 2;    // 1600000
    const int* row = ei;
    const int* col = ei + E;
    int nb = (N + (1 << BKT_SH) - 1) >> BKT_SH;  // 782 buckets

    char* ws = (char*)d_ws;
    int* cursor = (int*)ws;                          // nb ints @ 0
    int* start = (int*)(ws + (1 << 16));             // N ints @ 64 KB
    int* cntarr = (int*)(ws + (1 << 19));            // N ints @ 512 KB
    float* dinv = (float*)(ws + 960 * 1024);         // N floats @ 960 KB
    unsigned* bentries = (unsigned*)(ws + (2 << 20));    // nb*CAP u32 @ 2 MB (12.8 MB)
    unsigned short* Ab = (unsigned short*)(ws + (15 << 20));  // N*64 bf16 @ 15 MB (12.8 MB)
    unsigned short* Hb = (unsigned short*)d_out;     // bf16 h2 scratch in d_out
    float* OUTF = (float*)d_out;                     // final fp32 output

    int gemmblk = (N + BM - 1) / BM;       // 1563
    int binblk = (E + CHUNK - 1) / CHUNK;  // 261
    int gblk = (N * 8 + 255) / 256;        // 3125

    // --- CSR build (padded buckets; once, shared by both layers) ---
    k_zero_i<<<(nb + 255) / 256, 256, 0, stream>>>(cursor, nb);
    k_bin<<<binblk, NTB, 0, stream>>>(row, col, cursor, bentries, E);
    k_bucket_sort<<<nb, NTS, 0, stream>>>(bentries, cursor, start, cntarr, dinv, N);

    // Layer 1: Ab = bf16((X@W1)*dinv); Hb = bf16(relu(gather(Ab)*dinv + b1))
    k_gemm_f32in<<<gemmblk, 256, 0, stream>>>(x, W1, dinv, Ab, N, 128);
    k_gather<<<gblk, 256, 0, stream>>>((const uint4*)Ab, (const int*)bentries,
                                       start, cntarr, dinv, b1,
                                       nullptr, (uint4*)Hb, N, 1);

    // Layer 2: Ab = bf16((Hb@W2)*dinv); d_out = gather(Ab)*dinv + b2 (fp32)
    k_gemm_bf16in<<<gemmblk, 256, 0, stream>>>(Hb, W2, dinv, Ab, N, 64);
    k_gather<<<gblk, 256, 0, stream>>>((const uint4*)Ab, (const int*)bentries,
                                       start, cntarr, dinv, b2,
                                       OUTF, nullptr, N, 0);
}

// Round 11
// 227.858 us; speedup vs baseline: 1.0410x; 1.0121x over previous
//
#include <hip/hip_runtime.h>

// GCN 2-layer, CSR-gather formulation, padded-bucket CSR build.
//   out[c] = dinv[c] * ( h_s[c] + sum_{e: col=c} h_s[row_e] ) + b,  h_s=(X@W)*dinv
// R20: fused gather1+gemm2. gather1 produces h2[node] row entirely within one
// wave (8 lanes x 8ch); gemm2 consumes it row-locally. Fusion: W2 in LDS
// (16KB, staged once), h2 fp32 row -> wave-coherent LDS (no barrier: 8
// lanes/node = same wave), each lane computes 8 out-ch (512 FMA from LDS),
// x dinv, bf16-pack to Ab. Deletes gemm2 kernel + launch + 25.6MB Hb traffic;
// FMA hides under gather's idle VALU (gather is VMEM-latency-bound). Layer-2
// input now fp32 (was bf16 Hb) -> numerics closer to reference.
// gemm1 = R19's pipelined 64x64 (verified). Build chain = R17's 1024/512-thr.
// Lessons: R11 no 4B global scatter; R14 no LDS-atomic scatter; R15/R16 no
// mega-fusion; R19 staging pipeline works (load-early/write-late).
// Messages bf16, accum fp32. Requires N < 2^17. Int inputs arrive as int32.

#define BKT_SH 7            // 128 nodes per bucket
#define BKT_CAP 4096        // region per bucket (counts ~2046 +- 45; huge margin)
#define CHUNK 6144          // edges per k_bin block
#define NTB 1024            // k_bin threads
#define NTS 512             // k_bucket_sort threads
#define BM 64               // gemm rows/block
#define BK 32

__device__ __forceinline__ unsigned short f2bf(float f) {
    unsigned u = __builtin_bit_cast(unsigned, f);
    u = (u + 0x7FFF + ((u >> 16) & 1)) >> 16;  // RNE
    return (unsigned short)u;
}
__device__ __forceinline__ float bflo(unsigned u) {  // low bf16 of packed pair
    return __builtin_bit_cast(float, u << 16);
}
__device__ __forceinline__ float bfhi(unsigned u) {  // high bf16 of packed pair
    return __builtin_bit_cast(float, u & 0xFFFF0000u);
}

__global__ __launch_bounds__(256) void k_zero_i(int* __restrict__ p, int n) {
    int i = blockIdx.x * 256 + threadIdx.x;
    if (i < n) p[i] = 0;
}

// (A) block-chunked binning, 1024 threads: LDS hist -> LDS scan (t<256) ->
// one count-reservation atomic per (block,bucket) -> LDS sort by bucket ->
// run-coalesced writes into fixed bucket region [bkt*CAP, (bkt+1)*CAP).
__global__ __launch_bounds__(NTB) void k_bin(const int* __restrict__ row,
                                             const int* __restrict__ col,
                                             int* __restrict__ cursor,
                                             unsigned* __restrict__ bentries,
                                             int E) {
    __shared__ unsigned sorted[CHUNK];        // 24 KB packed entries, bucket order
    __shared__ unsigned short bof[CHUNK];     // 12 KB bucket of sorted[i]
    __shared__ int hist[1024];
    __shared__ int ex0[1024];
    __shared__ int cur[1024];
    __shared__ int gbase[1024];
    __shared__ int tsum[256];
    int b = blockIdx.x, t = threadIdx.x;
    int s0 = b * CHUNK;
    int cnt = E - s0; if (cnt > CHUNK) cnt = CHUNK;

    if (t < 1024) hist[t] = 0;
    __syncthreads();
    // pass 1: histogram
    for (int i = t; i < cnt; i += NTB)
        atomicAdd(&hist[col[s0 + i] >> BKT_SH], 1);
    __syncthreads();
    // scan 1024 bins on threads t<256 (each owns bins [4t, 4t+4));
    // all threads execute the __syncthreads.
    {
        int b0 = 0, b1 = 0, b2 = 0, b3 = 0, tot = 0;
        if (t < 256) {
            b0 = hist[4 * t]; b1 = hist[4 * t + 1];
            b2 = hist[4 * t + 2]; b3 = hist[4 * t + 3];
            tot = b0 + b1 + b2 + b3;
            tsum[t] = tot;
        }
        __syncthreads();
#pragma unroll
        for (int d = 1; d < 256; d <<= 1) {
            int x = 0;
            if (t < 256 && t >= d) x = tsum[t - d];
            __syncthreads();
            if (t < 256 && t >= d) tsum[t] += x;
            __syncthreads();
        }
        if (t < 256) {
            int ex = tsum[t] - tot;  // exclusive across thread groups
            ex0[4 * t] = ex;
            ex0[4 * t + 1] = ex + b0;
            ex0[4 * t + 2] = ex + b0 + b1;
            ex0[4 * t + 3] = ex + b0 + b1 + b2;
            cur[4 * t] = ex;
            cur[4 * t + 1] = ex + b0;
            cur[4 * t + 2] = ex + b0 + b1;
            cur[4 * t + 3] = ex + b0 + b1 + b2;
        }
    }
    __syncthreads();
    // reserve: one atomic per non-empty (block,bucket); region base is fixed
    if (t < 1024)
        if (hist[t] > 0) gbase[t] = t * BKT_CAP + atomicAdd(&cursor[t], hist[t]);
    // pass 2: LDS sort by bucket (order within bucket irrelevant)
    for (int i = t; i < cnt; i += NTB) {
        int c = col[s0 + i], r = row[s0 + i];
        int bkt = c >> BKT_SH;
        int p = atomicAdd(&cur[bkt], 1);
        sorted[p] = ((unsigned)(c & ((1 << BKT_SH) - 1)) << 17) | (unsigned)r;
        bof[p] = (unsigned short)bkt;
    }
    __syncthreads();
    // pass 3: run-coalesced global writes (guard against region overflow)
    for (int i = t; i < cnt; i += NTB) {
        int bkt = bof[i];
        int pos = gbase[bkt] + (i - ex0[bkt]);
        if (pos < (bkt + 1) * BKT_CAP) bentries[pos] = sorted[i];
    }
}

// (B) per-bucket counting sort IN PLACE, 512 threads: bentries[b*CAP..] ->
// row indices sorted by destination node; emits start/cnt/dinv per node.
__global__ __launch_bounds__(NTS) void k_bucket_sort(
    unsigned* __restrict__ bentries, const int* __restrict__ cursor,
    int* __restrict__ start, int* __restrict__ cntarr,
    float* __restrict__ dinv, int N) {
    __shared__ int hist[128];
    __shared__ int incl[128];
    __shared__ int cur[128];
    __shared__ int rows[BKT_CAP];  // 16 KB
    int b = blockIdx.x, t = threadIdx.x;
    int base = b * BKT_CAP;
    int cnt = cursor[b];
    if (cnt > BKT_CAP) cnt = BKT_CAP;  // safety clamp (never expected)

    if (t < 128) hist[t] = 0;
    __syncthreads();
    for (int i = t; i < cnt; i += NTS)
        atomicAdd(&hist[bentries[base + i] >> 17], 1);
    __syncthreads();
    if (t < 128) incl[t] = hist[t];
    __syncthreads();
#pragma unroll
    for (int d = 1; d < 128; d <<= 1) {
        int x = (t < 128 && t >= d) ? incl[t - d] : 0;
        __syncthreads();
        if (t < 128 && t >= d) incl[t] += x;
        __syncthreads();
    }
    if (t < 128) {
        int ex = incl[t] - hist[t];  // exclusive within bucket
        int node = (b << BKT_SH) + t;
        if (node < N) {
            start[node] = base + ex;
            cntarr[node] = hist[t];
            dinv[node] = rsqrtf((float)hist[t] + 1.0f);  // +1 self loop
        }
        cur[t] = ex;
    }
    __syncthreads();
    for (int i = t; i < cnt; i += NTS) {
        unsigned en = bentries[base + i];
        int p = atomicAdd(&cur[en >> 17], 1);
        rows[p] = (int)(en & 0x1FFFF);
    }
    __syncthreads();
    for (int i = t; i < cnt; i += NTS) bentries[base + i] = (unsigned)rows[i];
}

// Tiled GEMM + row scale, fp32 input, bf16 output. 64x64 tile, acc 4x4.
// Software-pipelined: next K-tile's global loads issued into registers BEFORE
// the FMA loop; ds_write after the post-compute barrier. Pad +1 (free alias).
__global__ __launch_bounds__(256) void k_gemm_f32in(
    const float* __restrict__ X, const float* __restrict__ W,
    const float* __restrict__ dinv, unsigned short* __restrict__ outb,
    int N, int K) {
    __shared__ float Xs[BK][BM + 1];
    __shared__ float Ws[BK][64];
    int t = threadIdx.x;
    int bm = blockIdx.x * BM;
    int tm = t >> 4, tn = t & 15;
    int sr = t >> 3;                 // staging row base (0..31), +32 for it=1
    int sk4 = t & 7;                 // staging float4 index within BK

    float4 rx0, rx1, rw0, rw1;

#define LOADT(kb)                                                              \
    {                                                                          \
        int g0 = bm + sr, g1 = bm + sr + 32;                                   \
        rx0 = make_float4(0.f, 0.f, 0.f, 0.f);                                 \
        rx1 = make_float4(0.f, 0.f, 0.f, 0.f);                                 \
        if (g0 < N) rx0 = *(const float4*)(X + (size_t)g0 * K + (kb) + sk4 * 4);\
        if (g1 < N) rx1 = *(const float4*)(X + (size_t)g1 * K + (kb) + sk4 * 4);\
        rw0 = ((const float4*)(W + (size_t)(kb) * 64))[t];                     \
        rw1 = ((const float4*)(W + (size_t)(kb) * 64))[t + 256];               \
    }
#define WRITET()                                                               \
    {                                                                          \
        Xs[sk4 * 4 + 0][sr] = rx0.x; Xs[sk4 * 4 + 1][sr] = rx0.y;              \
        Xs[sk4 * 4 + 2][sr] = rx0.z; Xs[sk4 * 4 + 3][sr] = rx0.w;              \
        Xs[sk4 * 4 + 0][sr + 32] = rx1.x; Xs[sk4 * 4 + 1][sr + 32] = rx1.y;    \
        Xs[sk4 * 4 + 2][sr + 32] = rx1.z; Xs[sk4 * 4 + 3][sr + 32] = rx1.w;    \
        ((float4*)Ws)[t] = rw0;                                                \
        ((float4*)Ws)[t + 256] = rw1;                                          \
    }

    float acc[4][4];
#pragma unroll
    for (int i = 0; i < 4; ++i)
#pragma unroll
        for (int j = 0; j < 4; ++j) acc[i][j] = 0.f;

    LOADT(0);
    WRITET();
    __syncthreads();
    for (int kb = 0; kb < K; kb += BK) {
        bool more = (kb + BK) < K;
        if (more) LOADT(kb + BK);    // in flight during compute
#pragma unroll
        for (int k = 0; k < BK; ++k) {
            float4 xa = *(const float4*)&Xs[k][tm * 4];
            float4 w = *(const float4*)&Ws[k][tn * 4];
            float xs[4] = {xa.x, xa.y, xa.z, xa.w};
#pragma unroll
            for (int i = 0; i < 4; ++i) {
                acc[i][0] = fmaf(xs[i], w.x, acc[i][0]);
                acc[i][1] = fmaf(xs[i], w.y, acc[i][1]);
                acc[i][2] = fmaf(xs[i], w.z, acc[i][2]);
                acc[i][3] = fmaf(xs[i], w.w, acc[i][3]);
            }
        }
        __syncthreads();
        if (more) {
            WRITET();
            __syncthreads();
        }
    }
#pragma unroll
    for (int i = 0; i < 4; ++i) {
        int grow = bm + tm * 4 + i;
        if (grow < N) {
            float s = dinv[grow];
            ushort4 v;
            v.x = f2bf(acc[i][0] * s);
            v.y = f2bf(acc[i][1] * s);
            v.z = f2bf(acc[i][2] * s);
            v.w = f2bf(acc[i][3] * s);
            *(ushort4*)(outb + (size_t)grow * 64 + tn * 4) = v;
        }
    }
#undef LOADT
#undef WRITET
}

// (C) FUSED gather1 + gemm2. 8 lanes/node (32 nodes/block). Gather h2 row
// in fp32 (dinv*sum + b1, relu), write to wave-coherent LDS row (8 lanes of
// a node = same wave -> no barrier), then each lane computes its 8 output
// channels of h2 @ W2 from LDS, scales by dinv, bf16-packs into Ab.
__global__ __launch_bounds__(256) void k_gather_gemm2(
    const uint4* __restrict__ srcq, const int* __restrict__ eros,
    const int* __restrict__ start, const int* __restrict__ cntarr,
    const float* __restrict__ dinv, const float* __restrict__ bias1,
    const float* __restrict__ W2, unsigned short* __restrict__ outAb, int N) {
    __shared__ float w2s[64][64];   // 16 KB
    __shared__ float h2s[32][68];   // 8.7 KB (stride 68: 16B-aligned rows,
                                    // banks nl*4 mod 32 distinct per wave)
    int t = threadIdx.x;
    // stage W2: 1024 float4, 4 per thread
    {
        const float4* wg = (const float4*)W2;
        float4* wsp = (float4*)w2s;
        wsp[t] = wg[t];
        wsp[t + 256] = wg[t + 256];
        wsp[t + 512] = wg[t + 512];
        wsp[t + 768] = wg[t + 768];
    }
    __syncthreads();

    int idx = blockIdx.x * 256 + t;
    int node = idx >> 3;
    if (node >= N) return;
    int l = idx & 7;
    int nl = t >> 3;   // node-local index within block (0..31)

    // ---- gather phase (identical math to k_gather mode 1) ----
    uint4 sv = srcq[(size_t)node * 8 + l];  // self loop
    float a0 = bflo(sv.x), a1 = bfhi(sv.x);
    float a2 = bflo(sv.y), a3 = bfhi(sv.y);
    float a4 = bflo(sv.z), a5 = bfhi(sv.z);
    float a6 = bflo(sv.w), a7 = bfhi(sv.w);

    int e = start[node];
    int eend = e + cntarr[node];
    for (; e + 8 <= eend; e += 8) {
        uint4 v[8];
#pragma unroll
        for (int j = 0; j < 8; ++j) {
            int r = eros[e + j];
            v[j] = srcq[(size_t)r * 8 + l];
        }
#pragma unroll
        for (int j = 0; j < 8; ++j) {
            a0 += bflo(v[j].x); a1 += bfhi(v[j].x);
            a2 += bflo(v[j].y); a3 += bfhi(v[j].y);
            a4 += bflo(v[j].z); a5 += bfhi(v[j].z);
            a6 += bflo(v[j].w); a7 += bfhi(v[j].w);
        }
    }
    for (; e + 4 <= eend; e += 4) {
        uint4 v[4];
#pragma unroll
        for (int j = 0; j < 4; ++j) {
            int r = eros[e + j];
            v[j] = srcq[(size_t)r * 8 + l];
        }
#pragma unroll
        for (int j = 0; j < 4; ++j) {
            a0 += bflo(v[j].x); a1 += bfhi(v[j].x);
            a2 += bflo(v[j].y); a3 += bfhi(v[j].y);
            a4 += bflo(v[j].z); a5 += bfhi(v[j].z);
            a6 += bflo(v[j].w); a7 += bfhi(v[j].w);
        }
    }
    for (; e < eend; ++e) {
        int r = eros[e];
        uint4 v = srcq[(size_t)r * 8 + l];
        a0 += bflo(v.x); a1 += bfhi(v.x);
        a2 += bflo(v.y); a3 += bfhi(v.y);
        a4 += bflo(v.z); a5 += bfhi(v.z);
        a6 += bflo(v.w); a7 += bfhi(v.w);
    }
    float sc = dinv[node];
    {
        const float4* bp = (const float4*)bias1;
        float4 b0 = bp[l * 2], b1v = bp[l * 2 + 1];
        a0 = fmaxf(a0 * sc + b0.x, 0.f);  a1 = fmaxf(a1 * sc + b0.y, 0.f);
        a2 = fmaxf(a2 * sc + b0.z, 0.f);  a3 = fmaxf(a3 * sc + b0.w, 0.f);
        a4 = fmaxf(a4 * sc + b1v.x, 0.f); a5 = fmaxf(a5 * sc + b1v.y, 0.f);
        a6 = fmaxf(a6 * sc + b1v.z, 0.f); a7 = fmaxf(a7 * sc + b1v.w, 0.f);
    }
    // publish h2 row segment (wave-coherent: consumers are the same wave)
    *(float4*)&h2s[nl][l * 8] = make_float4(a0, a1, a2, a3);
    *(float4*)&h2s[nl][l * 8 + 4] = make_float4(a4, a5, a6, a7);

    // ---- gemm2 phase: out[ch = l*8 + j] = sum_k h2[k] * W2[k][ch] ----
    float o0 = 0.f, o1 = 0.f, o2 = 0.f, o3 = 0.f;
    float o4 = 0.f, o5 = 0.f, o6 = 0.f, o7 = 0.f;
#pragma unroll 4
    for (int k0 = 0; k0 < 64; k0 += 4) {
        float4 h4 = *(const float4*)&h2s[nl][k0];
        float hs[4] = {h4.x, h4.y, h4.z, h4.w};
#pragma unroll
        for (int j = 0; j < 4; ++j) {
            float h = hs[j];
            float4 wA = *(const float4*)&w2s[k0 + j][l * 8];
            float4 wB = *(const float4*)&w2s[k0 + j][l * 8 + 4];
            o0 = fmaf(h, wA.x, o0); o1 = fmaf(h, wA.y, o1);
            o2 = fmaf(h, wA.z, o2); o3 = fmaf(h, wA.w, o3);
            o4 = fmaf(h, wB.x, o4); o5 = fmaf(h, wB.y, o5);
            o6 = fmaf(h, wB.z, o6); o7 = fmaf(h, wB.w, o7);
        }
    }
    // epilogue: Ab = bf16(out * dinv)
    uint4 ov;
    ov.x = (unsigned)f2bf(o0 * sc) | ((unsigned)f2bf(o1 * sc) << 16);
    ov.y = (unsigned)f2bf(o2 * sc) | ((unsigned)f2bf(o3 * sc) << 16);
    ov.z = (unsigned)f2bf(o4 * sc) | ((unsigned)f2bf(o5 * sc) << 16);
    ov.w = (unsigned)f2bf(o6 * sc) | ((unsigned)f2bf(o7 * sc) << 16);
    *(uint4*)(outAb + (size_t)node * 64 + l * 8) = ov;
}

// Gather-aggregate + fused postproc (layer 2). 8 lanes/node; fp32 out.
__global__ __launch_bounds__(256) void k_gather(
    const uint4* __restrict__ srcq, const int* __restrict__ eros,
    const int* __restrict__ start, const int* __restrict__ cntarr,
    const float* __restrict__ dinv, const float* __restrict__ bias,
    float* __restrict__ dstf, int N) {
    int idx = blockIdx.x * 256 + threadIdx.x;
    int node = idx >> 3;
    if (node >= N) return;
    int l = idx & 7;

    uint4 sv = srcq[(size_t)node * 8 + l];  // self loop
    float a0 = bflo(sv.x), a1 = bfhi(sv.x);
    float a2 = bflo(sv.y), a3 = bfhi(sv.y);
    float a4 = bflo(sv.z), a5 = bfhi(sv.z);
    float a6 = bflo(sv.w), a7 = bfhi(sv.w);

    int e = start[node];
    int eend = e + cntarr[node];
    for (; e + 8 <= eend; e += 8) {
        uint4 v[8];
#pragma unroll
        for (int j = 0; j < 8; ++j) {
            int r = eros[e + j];
            v[j] = srcq[(size_t)r * 8 + l];
        }
#pragma unroll
        for (int j = 0; j < 8; ++j) {
            a0 += bflo(v[j].x); a1 += bfhi(v[j].x);
            a2 += bflo(v[j].y); a3 += bfhi(v[j].y);
            a4 += bflo(v[j].z); a5 += bfhi(v[j].z);
            a6 += bflo(v[j].w); a7 += bfhi(v[j].w);
        }
    }
    for (; e + 4 <= eend; e += 4) {
        uint4 v[4];
#pragma unroll
        for (int j = 0; j < 4; ++j) {
            int r = eros[e + j];
            v[j] = srcq[(size_t)r * 8 + l];
        }
#pragma unroll
        for (int j = 0; j < 4; ++j) {
            a0 += bflo(v[j].x); a1 += bfhi(v[j].x);
            a2 += bflo(v[j].y); a3 += bfhi(v[j].y);
            a4 += bflo(v[j].z); a5 += bfhi(v[j].z);
            a6 += bflo(v[j].w); a7 += bfhi(v[j].w);
        }
    }
    for (; e < eend; ++e) {
        int r = eros[e];
        uint4 v = srcq[(size_t)r * 8 + l];
        a0 += bflo(v.x); a1 += bfhi(v.x);
        a2 += bflo(v.y); a3 += bfhi(v.y);
        a4 += bflo(v.z); a5 += bfhi(v.z);
        a6 += bflo(v.w); a7 += bfhi(v.w);
    }
    float sc = dinv[node];
    const float4* bp = (const float4*)bias;
    float4 b0 = bp[l * 2], b1 = bp[l * 2 + 1];
    a0 = a0 * sc + b0.x; a1 = a1 * sc + b0.y;
    a2 = a2 * sc + b0.z; a3 = a3 * sc + b0.w;
    a4 = a4 * sc + b1.x; a5 = a5 * sc + b1.y;
    a6 = a6 * sc + b1.z; a7 = a7 * sc + b1.w;
    float4 o0 = make_float4(a0, a1, a2, a3);
    float4 o1 = make_float4(a4, a5, a6, a7);
    float4* d = (float4*)(dstf + (size_t)node * 64 + l * 8);
    d[0] = o0;
    d[1] = o1;
}

extern "C" void kernel_launch(void* const* d_in, const int* in_sizes, int n_in,
                              void* d_out, int out_size, void* d_ws, size_t ws_size,
                              hipStream_t stream) {
    const float* x = (const float*)d_in[0];
    const int* ei = (const int*)d_in[1];  // int32 per harness contract, [2, E]
    const float* W1 = (const float*)d_in[2];
    const float* b1 = (const float*)d_in[3];
    const float* W2 = (const float*)d_in[4];
    const float* b2 = (const float*)d_in[5];

    int N = in_sizes[0] / 128;  // 100000
    int E = in_sizes[1] / 2;    // 1600000
    const int* row = ei;
    const int* col = ei + E;
    int nb = (N + (1 << BKT_SH) - 1) >> BKT_SH;  // 782 buckets

    char* ws = (char*)d_ws;
    int* cursor = (int*)ws;                          // nb ints @ 0
    int* start = (int*)(ws + (1 << 16));             // N ints @ 64 KB
    int* cntarr = (int*)(ws + (1 << 19));            // N ints @ 512 KB
    float* dinv = (float*)(ws + 960 * 1024);         // N floats @ 960 KB
    unsigned* bentries = (unsigned*)(ws + (2 << 20));    // nb*CAP u32 @ 2 MB (12.8 MB)
    unsigned short* Ab = (unsigned short*)(ws + (15 << 20));   // N*64 bf16 @ 15 MB
    unsigned short* Ab2 = (unsigned short*)(ws + (28 << 20));  // N*64 bf16 @ 28 MB
    float* OUTF = (float*)d_out;                     // final fp32 output

    int gemmblk = (N + BM - 1) / BM;       // 1563
    int binblk = (E + CHUNK - 1) / CHUNK;  // 261
    int gblk = (N * 8 + 255) / 256;        // 3125

    // --- CSR build (padded buckets; once, shared by both layers) ---
    k_zero_i<<<(nb + 255) / 256, 256, 0, stream>>>(cursor, nb);
    k_bin<<<binblk, NTB, 0, stream>>>(row, col, cursor, bentries, E);
    k_bucket_sort<<<nb, NTS, 0, stream>>>(bentries, cursor, start, cntarr, dinv, N);

    // Layer 1 GEMM: Ab = bf16((X@W1)*dinv)
    k_gemm_f32in<<<gemmblk, 256, 0, stream>>>(x, W1, dinv, Ab, N, 128);
    // Fused: h2 = relu(gather(Ab)*dinv + b1);  Ab2 = bf16((h2@W2)*dinv)
    k_gather_gemm2<<<gblk, 256, 0, stream>>>((const uint4*)Ab, (const int*)bentries,
                                             start, cntarr, dinv, b1, W2, Ab2, N);
    // Layer 2 gather: d_out = gather(Ab2)*dinv + b2 (fp32)
    k_gather<<<gblk, 256, 0, stream>>>((const uint4*)Ab2, (const int*)bentries,
                                       start, cntarr, dinv, b2, OUTF, N);
}